// Round 1
// baseline (146.216 us; speedup 1.0000x reference)
//
#include <hip/hip_runtime.h>
#include <hip/hip_bf16.h>

#define BB     8
#define IN_PNN 4096
#define OUT_PNN 2048
#define MM     16
#define WWN    32
#define ICC    32
#define OCC    64

// ws layout: [0, 262144) bytes : Kt2  (256 kb x 64 o x 4 j) floats  = kern[w,o,i] re-tiled k-major->o-major
//            [262144, 270336)  : wrest (32 i x 64 o) floats         = weight_res transposed

__global__ __launch_bounds__(256) void prep_kernel(const float* __restrict__ weights,
                                                   const float* __restrict__ wres,
                                                   float* __restrict__ kt2,
                                                   float* __restrict__ wrt) {
  int t = blockIdx.x * 256 + threadIdx.x;
  if (t < WWN * OCC * ICC) {              // 65536
    int kb = t >> 8;                      // 0..255
    int o  = (t >> 2) & 63;
    int j  = t & 3;
    int k  = kb * 4 + j;                  // k = w*32 + i
    int w  = k >> 5;
    int i  = k & 31;
    kt2[t] = weights[w * (OCC * ICC) + o * ICC + i];
  }
  if (t < ICC * OCC) {                    // 2048
    int i = t >> 6;
    int o = t & 63;
    wrt[t] = wres[o * ICC + i];
  }
}

__global__ __launch_bounds__(256) void fused_kernel(
    const float* __restrict__ in_pc,   // [B][IN_PN][IC]
    const float* __restrict__ bias,    // [OC]
    const float* __restrict__ ww,      // [OUT_PN][M][W]
    const float* __restrict__ praw,    // [OUT_PN][M]
    const int*   __restrict__ nid,     // [OUT_PN][M]
    const float* __restrict__ kt2,     // [256][64][4]
    const float* __restrict__ wrt,     // [32][64]
    float*       __restrict__ out) {   // [B][OUT_PN][OC]

  __shared__ float s_ww[MM][WWN];        // masked w_weights, 2 KB
  __shared__ float s_p[MM];              // |praw|*mask (unnormalized)
  __shared__ int   s_nid[MM];
  __shared__ float s_pinv;
  __shared__ float s_q[ICC][BB];         // q[i][b], 1 KB
  __shared__ float s_h2[256][BB][4];     // h re-tiled: [kb][b ^ (kb&7)][j], 32 KB

  const int p   = blockIdx.x;
  const int tid = threadIdx.x;

  // ---------- Phase A: per-p metadata ----------
  if (tid < MM) {
    int id = nid[p * MM + tid];
    s_nid[tid] = id;
    float mask = (id != IN_PNN) ? 1.f : 0.f;
    s_p[tid] = fabsf(praw[p * MM + tid]) * mask;
  }
  for (int e = tid; e < MM * WWN; e += 256) {
    int m = e >> 5;
    int id = nid[p * MM + m];
    float mask = (id != IN_PNN) ? 1.f : 0.f;
    s_ww[m][e & 31] = ww[p * MM * WWN + e] * mask;
  }
  __syncthreads();
  if (tid == 0) {
    float s = 1e-8f;
#pragma unroll
    for (int m = 0; m < MM; m++) s += s_p[m];
    s_pinv = 1.f / s;
  }
  __syncthreads();

  // ---------- Phase B: gather neighbors, build h[w] and q per (b, i) ----------
  {
    const int b = tid >> 5;        // 0..7
    const int i = tid & 31;        // lane within group = channel
    const float* pc = in_pc + (size_t)b * IN_PNN * ICC + i;

    float nbr[MM];
#pragma unroll
    for (int m = 0; m < MM; m++) {
      int id = s_nid[m];
      nbr[m] = (id < IN_PNN) ? pc[id * ICC] : 0.f;
    }

    float h[WWN];
#pragma unroll
    for (int w = 0; w < WWN; w++) h[w] = 0.f;
#pragma unroll
    for (int m = 0; m < MM; m++) {
      float v = nbr[m];
#pragma unroll
      for (int w = 0; w < WWN; w += 4) {
        float4 c = *(const float4*)&s_ww[m][w];
        h[w + 0] += c.x * v;
        h[w + 1] += c.y * v;
        h[w + 2] += c.z * v;
        h[w + 3] += c.w * v;
      }
    }

    float q = 0.f;
    float pinv = s_pinv;
#pragma unroll
    for (int m = 0; m < MM; m++) q += s_p[m] * nbr[m];
    q *= pinv;
    s_q[i][b] = q;

    // scatter h into k-major tile with bank-conflict-free XOR swizzle on b
#pragma unroll
    for (int w = 0; w < WWN; w++) {
      int kb = w * 8 + (i >> 2);   // k = w*32 + i ; kb = k>>2
      s_h2[kb][b ^ (kb & 7)][i & 3] = h[w];
    }
  }
  __syncthreads();

  // ---------- Phase C: out[b,o] = K^T h + residual, lane = o ----------
  {
    const int wv = tid >> 6;       // wave 0..3 -> batches (2wv, 2wv+1)
    const int o  = tid & 63;
    const int b0 = 2 * wv, b1 = 2 * wv + 1;

    float acc0 = 0.f, acc1 = 0.f;
    const float4* K4 = (const float4*)kt2;   // K4[kb*64 + o]
#pragma unroll 4
    for (int kb = 0; kb < 256; kb++) {
      float4 kv = K4[kb * 64 + o];
      int sw = kb & 7;
      float4 h0 = *(const float4*)&s_h2[kb][b0 ^ sw][0];
      float4 h1 = *(const float4*)&s_h2[kb][b1 ^ sw][0];
      acc0 = fmaf(kv.x, h0.x, acc0); acc0 = fmaf(kv.y, h0.y, acc0);
      acc0 = fmaf(kv.z, h0.z, acc0); acc0 = fmaf(kv.w, h0.w, acc0);
      acc1 = fmaf(kv.x, h1.x, acc1); acc1 = fmaf(kv.y, h1.y, acc1);
      acc1 = fmaf(kv.z, h1.z, acc1); acc1 = fmaf(kv.w, h1.w, acc1);
    }

    // residual: out_res[b,o] = sum_i wrest[i][o] * q[i][b]
    float rs0 = 0.f, rs1 = 0.f;
#pragma unroll
    for (int i = 0; i < ICC; i++) {
      float wv_ = wrt[i * 64 + o];
      rs0 = fmaf(wv_, s_q[i][b0], rs0);
      rs1 = fmaf(wv_, s_q[i][b1], rs1);
    }

    float bo = bias[o];
    float c0 = acc0 + bo;
    float c1 = acc1 + bo;
    c0 = (c0 > 0.f) ? c0 : (__expf(c0) - 1.f);   // ELU
    c1 = (c1 > 0.f) ? c1 : (__expf(c1) - 1.f);
    const float r = 0.70710678118654752f;        // sqrt(0.5) = both mix weights
    out[((size_t)b0 * OUT_PNN + p) * OCC + o] = r * c0 + r * rs0;
    out[((size_t)b1 * OUT_PNN + p) * OCC + o] = r * c1 + r * rs1;
  }
}

extern "C" void kernel_launch(void* const* d_in, const int* in_sizes, int n_in,
                              void* d_out, int out_size, void* d_ws, size_t ws_size,
                              hipStream_t stream) {
  const float* in_pc   = (const float*)d_in[0];
  const float* weights = (const float*)d_in[1];
  const float* bias    = (const float*)d_in[2];
  const float* w_w     = (const float*)d_in[3];
  const float* praw    = (const float*)d_in[4];
  const float* wres    = (const float*)d_in[5];
  const int*   nid     = (const int*)d_in[6];
  float* outp = (float*)d_out;

  float* kt2 = (float*)d_ws;          // 65536 floats
  float* wrt = kt2 + 65536;           // 2048 floats

  prep_kernel<<<256, 256, 0, stream>>>(weights, wres, kt2, wrt);
  fused_kernel<<<OUT_PNN, 256, 0, stream>>>(in_pc, bias, w_w, praw, nid, kt2, wrt, outp);
}

// Round 2
// 104.587 us; speedup vs baseline: 1.3980x; 1.3980x over previous
//
#include <hip/hip_runtime.h>
#include <hip/hip_bf16.h>

#define BB      8
#define IN_PNN  4096
#define OUT_PNN 2048
#define MM      16
#define WWN     32
#define ICC     32
#define OCC     64

typedef __attribute__((ext_vector_type(8))) short short8;
typedef __attribute__((ext_vector_type(4))) float f32x4;

// ===================== MFMA path =====================
// ws layout:
//   [0, 131072)            ktb  bf16 [64 o][1024 k]   (B^T: ktb[o][k] = weights[w, o, i], k=w*32+i)
//   [131072, 139264)       wrt  f32  [32 i][64 o]
//   [262144, 33816576)     Ah   bf16 [16384 r][1024 k]  r = p*8 + b
//   [33816576, 38010880)   resb f32  [16384 r][64 o]

__global__ __launch_bounds__(256) void prep2_kernel(const float* __restrict__ weights,
                                                    const float* __restrict__ wres,
                                                    __hip_bfloat16* __restrict__ ktb,
                                                    float* __restrict__ wrt) {
  int t = blockIdx.x * 256 + threadIdx.x;
  if (t < WWN * OCC * ICC) {               // 65536
    int o = t >> 10, k = t & 1023;
    int w = k >> 5, i = k & 31;
    ktb[t] = __float2bfloat16(weights[w * (OCC * ICC) + o * ICC + i]);
  }
  if (t < ICC * OCC) {                     // 2048 : wrt[i*64+o] = wres[o*32+i]
    int i = t >> 6, o = t & 63;
    wrt[t] = wres[o * ICC + i];
  }
}

__global__ __launch_bounds__(256) void hq_kernel(
    const float* __restrict__ in_pc,   // [B][IN_PN][IC]
    const float* __restrict__ ww,      // [OUT_PN][M][W]
    const float* __restrict__ praw,    // [OUT_PN][M]
    const int*   __restrict__ nid,     // [OUT_PN][M]
    const float* __restrict__ wrt,     // [32][64]
    char*        __restrict__ Ahb,     // bf16 h out
    float*       __restrict__ resb) {  // residual out
  __shared__ float s_ww[MM][WWN];
  __shared__ int   s_nid[MM];
  __shared__ float s_p[MM];
  __shared__ float s_q[ICC][BB];
  __shared__ float s_wrt[ICC * OCC];
  __shared__ __align__(16) unsigned short s_hb[BB][1024];   // bf16 [b][k]

  const int p   = blockIdx.x;
  const int tid = threadIdx.x;

  if (tid < MM) {
    int id = nid[p * MM + tid];
    s_nid[tid] = id;
    s_p[tid] = (id != IN_PNN) ? fabsf(praw[p * MM + tid]) : 0.f;
  }
  for (int e = tid; e < MM * WWN; e += 256) {
    int m = e >> 5;
    int id = nid[p * MM + m];
    s_ww[m][e & 31] = (id != IN_PNN) ? ww[p * MM * WWN + e] : 0.f;
  }
  for (int e = tid; e < ICC * OCC; e += 256) s_wrt[e] = wrt[e];
  __syncthreads();

  float psum = 1e-8f;
#pragma unroll
  for (int m = 0; m < MM; ++m) psum += s_p[m];
  const float pinv = 1.f / psum;

  {
    const int b = tid >> 5, i = tid & 31;
    const float* pc = in_pc + (size_t)b * IN_PNN * ICC + i;
    float nbr[MM];
#pragma unroll
    for (int m = 0; m < MM; ++m) {
      int id = s_nid[m];
      nbr[m] = (id < IN_PNN) ? pc[(size_t)id * ICC] : 0.f;
    }
    float h[WWN];
#pragma unroll
    for (int w = 0; w < WWN; ++w) h[w] = 0.f;
#pragma unroll
    for (int m = 0; m < MM; ++m) {
      float v = nbr[m];
#pragma unroll
      for (int w = 0; w < WWN; w += 4) {
        float4 c = *(const float4*)&s_ww[m][w];
        h[w + 0] = fmaf(c.x, v, h[w + 0]);
        h[w + 1] = fmaf(c.y, v, h[w + 1]);
        h[w + 2] = fmaf(c.z, v, h[w + 2]);
        h[w + 3] = fmaf(c.w, v, h[w + 3]);
      }
    }
    float q = 0.f;
#pragma unroll
    for (int m = 0; m < MM; ++m) q = fmaf(s_p[m], nbr[m], q);
    s_q[i][b] = q * pinv;
#pragma unroll
    for (int w = 0; w < WWN; ++w) {
      __hip_bfloat16 hb = __float2bfloat16(h[w]);
      s_hb[b][w * 32 + i] = *(unsigned short*)&hb;
    }
  }
  __syncthreads();

  // store h slab: 16 KB contiguous (rows r=p*8+b, k-major)
  {
    const uint4* src = (const uint4*)&s_hb[0][0];
    uint4* dst = (uint4*)(Ahb + (size_t)p * 16384);
    for (int e = tid; e < 1024; e += 256) dst[e] = src[e];
  }
  // residual: resb[r][o] = sum_i wrt[i][o] * q[i][b]
  {
    const int b = tid >> 5, oo = tid & 31;
    float r0 = 0.f, r1 = 0.f;
#pragma unroll
    for (int i2 = 0; i2 < ICC; ++i2) {
      float qv = s_q[i2][b];
      r0 = fmaf(s_wrt[i2 * 64 + oo],      qv, r0);
      r1 = fmaf(s_wrt[i2 * 64 + oo + 32], qv, r1);
    }
    resb[((size_t)p * 8 + b) * 64 + oo]      = r0;
    resb[((size_t)p * 8 + b) * 64 + oo + 32] = r1;
  }
}

// 64 rows x 64 cols x K=1024 per block; 4 waves in 2x2; 16x16x32 bf16 MFMA.
// LDS: A[2][64][64] bf16 (8KB x2) + B[2][64][64] bf16; 128B rows, XOR swizzle col16^=(row&7).
__global__ __launch_bounds__(256) void gemm_kernel(
    const char* __restrict__ Ahb,    // bf16 [16384][1024]
    const char* __restrict__ ktbb,   // bf16 [64][1024]
    const float* __restrict__ resb,  // [16384][64]
    const float* __restrict__ bias,  // [64]
    float* __restrict__ out) {       // [B][OUT_PN][OC]
  __shared__ __align__(16) unsigned char sm[32768];

  const int tid = threadIdx.x;
  const int g   = blockIdx.x;
  const int l   = tid & 63;
  const int wv  = tid >> 6;
  const int wr  = wv >> 1, wc = wv & 1;

  // reg-staging: 512 16B-slots per matrix per K-chunk; 2 slots/thread
  const int s0 = tid, s1 = tid + 256;
  const int r0 = s0 >> 3, c0 = s0 & 7;
  const int r1 = s1 >> 3, c1 = s1 & 7;
  const char* a0p = Ahb  + ((size_t)(64 * g + r0) * 1024 + c0 * 8) * 2;
  const char* a1p = Ahb  + ((size_t)(64 * g + r1) * 1024 + c1 * 8) * 2;
  const char* b0p = ktbb + ((size_t)r0 * 1024 + c0 * 8) * 2;
  const char* b1p = ktbb + ((size_t)r1 * 1024 + c1 * 8) * 2;
  const int la0 = r0 * 128 + ((c0 ^ (r0 & 7)) * 16);
  const int la1 = r1 * 128 + ((c1 ^ (r1 & 7)) * 16);

  uint4 ra0 = *(const uint4*)(a0p);
  uint4 ra1 = *(const uint4*)(a1p);
  uint4 rb0 = *(const uint4*)(b0p);
  uint4 rb1 = *(const uint4*)(b1p);

  f32x4 acc[2][2];
#pragma unroll
  for (int R = 0; R < 2; ++R)
#pragma unroll
    for (int Q = 0; Q < 2; ++Q)
#pragma unroll
      for (int j = 0; j < 4; ++j) acc[R][Q][j] = 0.f;

  // fragment read byte-offsets (within one 8KB buffer)
  int aoff[2][2], boff[2][2];
#pragma unroll
  for (int R = 0; R < 2; ++R)
#pragma unroll
    for (int s = 0; s < 2; ++s) {
      int row = 32 * wr + 16 * R + (l & 15);
      aoff[R][s] = row * 128 + (((4 * s + (l >> 4)) ^ (row & 7)) * 16);
      int o = 32 * wc + 16 * R + (l & 15);
      boff[R][s] = o * 128 + (((4 * s + (l >> 4)) ^ (o & 7)) * 16);
    }

  for (int kt = 0; kt < 16; ++kt) {
    unsigned char* Ab = sm + (kt & 1) * 8192;
    unsigned char* Bb = sm + 16384 + (kt & 1) * 8192;
    *(uint4*)(Ab + la0) = ra0;
    *(uint4*)(Ab + la1) = ra1;
    *(uint4*)(Bb + la0) = rb0;
    *(uint4*)(Bb + la1) = rb1;
    if (kt < 15) {
      int ko = (kt + 1) * 128;      // 64 bf16 = 128 bytes per chunk-step
      ra0 = *(const uint4*)(a0p + ko);
      ra1 = *(const uint4*)(a1p + ko);
      rb0 = *(const uint4*)(b0p + ko);
      rb1 = *(const uint4*)(b1p + ko);
    }
    __syncthreads();                 // one barrier/iter; buffers alternate (see dbuf hazard proof)
    short8 aF[2][2], bF[2][2];
#pragma unroll
    for (int R = 0; R < 2; ++R)
#pragma unroll
      for (int s = 0; s < 2; ++s) {
        aF[R][s] = *(const short8*)(Ab + aoff[R][s]);
        bF[R][s] = *(const short8*)(Bb + boff[R][s]);
      }
#pragma unroll
    for (int R = 0; R < 2; ++R)
#pragma unroll
      for (int Q = 0; Q < 2; ++Q)
#pragma unroll
        for (int s = 0; s < 2; ++s)
          acc[R][Q] = __builtin_amdgcn_mfma_f32_16x16x32_bf16(aF[R][s], bF[Q][s], acc[R][Q], 0, 0, 0);
  }

  const float rmix = 0.70710678118654752f;
#pragma unroll
  for (int R = 0; R < 2; ++R)
#pragma unroll
    for (int Q = 0; Q < 2; ++Q)
#pragma unroll
      for (int j = 0; j < 4; ++j) {
        int rloc = 32 * wr + 16 * R + ((l >> 4) * 4) + j;   // C/D: row=(l>>4)*4+j, col=l&15
        int o    = 32 * wc + 16 * Q + (l & 15);
        int rg   = 64 * g + rloc;
        float v  = acc[R][Q][j] + bias[o];
        v = (v > 0.f) ? v : (__expf(v) - 1.f);
        float res = resb[(size_t)rg * 64 + o];
        int pp = rg >> 3, bb2 = rg & 7;
        out[((size_t)bb2 * OUT_PNN + pp) * OCC + o] = rmix * (v + res);
      }
}

// ===================== fallback path (round-1, known-good) =====================

__global__ __launch_bounds__(256) void prep_kernel(const float* __restrict__ weights,
                                                   const float* __restrict__ wres,
                                                   float* __restrict__ kt2,
                                                   float* __restrict__ wrt) {
  int t = blockIdx.x * 256 + threadIdx.x;
  if (t < WWN * OCC * ICC) {
    int kb = t >> 8;
    int o  = (t >> 2) & 63;
    int j  = t & 3;
    int k  = kb * 4 + j;
    int w  = k >> 5;
    int i  = k & 31;
    kt2[t] = weights[w * (OCC * ICC) + o * ICC + i];
  }
  if (t < ICC * OCC) {
    int i = t >> 6;
    int o = t & 63;
    wrt[t] = wres[o * ICC + i];
  }
}

__global__ __launch_bounds__(256) void fused_kernel(
    const float* __restrict__ in_pc,
    const float* __restrict__ bias,
    const float* __restrict__ ww,
    const float* __restrict__ praw,
    const int*   __restrict__ nid,
    const float* __restrict__ kt2,
    const float* __restrict__ wrt,
    float*       __restrict__ out) {
  __shared__ float s_ww[MM][WWN];
  __shared__ float s_p[MM];
  __shared__ int   s_nid[MM];
  __shared__ float s_pinv;
  __shared__ float s_q[ICC][BB];
  __shared__ float s_h2[256][BB][4];

  const int p   = blockIdx.x;
  const int tid = threadIdx.x;

  if (tid < MM) {
    int id = nid[p * MM + tid];
    s_nid[tid] = id;
    float mask = (id != IN_PNN) ? 1.f : 0.f;
    s_p[tid] = fabsf(praw[p * MM + tid]) * mask;
  }
  for (int e = tid; e < MM * WWN; e += 256) {
    int m = e >> 5;
    int id = nid[p * MM + m];
    float mask = (id != IN_PNN) ? 1.f : 0.f;
    s_ww[m][e & 31] = ww[p * MM * WWN + e] * mask;
  }
  __syncthreads();
  if (tid == 0) {
    float s = 1e-8f;
#pragma unroll
    for (int m = 0; m < MM; m++) s += s_p[m];
    s_pinv = 1.f / s;
  }
  __syncthreads();

  {
    const int b = tid >> 5;
    const int i = tid & 31;
    const float* pc = in_pc + (size_t)b * IN_PNN * ICC + i;
    float nbr[MM];
#pragma unroll
    for (int m = 0; m < MM; m++) {
      int id = s_nid[m];
      nbr[m] = (id < IN_PNN) ? pc[id * ICC] : 0.f;
    }
    float h[WWN];
#pragma unroll
    for (int w = 0; w < WWN; w++) h[w] = 0.f;
#pragma unroll
    for (int m = 0; m < MM; m++) {
      float v = nbr[m];
#pragma unroll
      for (int w = 0; w < WWN; w += 4) {
        float4 c = *(const float4*)&s_ww[m][w];
        h[w + 0] += c.x * v;
        h[w + 1] += c.y * v;
        h[w + 2] += c.z * v;
        h[w + 3] += c.w * v;
      }
    }
    float q = 0.f;
    float pinv = s_pinv;
#pragma unroll
    for (int m = 0; m < MM; m++) q += s_p[m] * nbr[m];
    q *= pinv;
    s_q[i][b] = q;
#pragma unroll
    for (int w = 0; w < WWN; w++) {
      int kb = w * 8 + (i >> 2);
      s_h2[kb][b ^ (kb & 7)][i & 3] = h[w];
    }
  }
  __syncthreads();

  {
    const int wv = tid >> 6;
    const int o  = tid & 63;
    const int b0 = 2 * wv, b1 = 2 * wv + 1;
    float acc0 = 0.f, acc1 = 0.f;
    const float4* K4 = (const float4*)kt2;
#pragma unroll 4
    for (int kb = 0; kb < 256; kb++) {
      float4 kv = K4[kb * 64 + o];
      int sw = kb & 7;
      float4 h0 = *(const float4*)&s_h2[kb][b0 ^ sw][0];
      float4 h1 = *(const float4*)&s_h2[kb][b1 ^ sw][0];
      acc0 = fmaf(kv.x, h0.x, acc0); acc0 = fmaf(kv.y, h0.y, acc0);
      acc0 = fmaf(kv.z, h0.z, acc0); acc0 = fmaf(kv.w, h0.w, acc0);
      acc1 = fmaf(kv.x, h1.x, acc1); acc1 = fmaf(kv.y, h1.y, acc1);
      acc1 = fmaf(kv.z, h1.z, acc1); acc1 = fmaf(kv.w, h1.w, acc1);
    }
    float rs0 = 0.f, rs1 = 0.f;
#pragma unroll
    for (int i = 0; i < ICC; i++) {
      float wv_ = wrt[i * 64 + o];
      rs0 = fmaf(wv_, s_q[i][b0], rs0);
      rs1 = fmaf(wv_, s_q[i][b1], rs1);
    }
    float bo = bias[o];
    float c0 = acc0 + bo;
    float c1 = acc1 + bo;
    c0 = (c0 > 0.f) ? c0 : (__expf(c0) - 1.f);
    c1 = (c1 > 0.f) ? c1 : (__expf(c1) - 1.f);
    const float r = 0.70710678118654752f;
    out[((size_t)b0 * OUT_PNN + p) * OCC + o] = r * c0 + r * rs0;
    out[((size_t)b1 * OUT_PNN + p) * OCC + o] = r * c1 + r * rs1;
  }
}

extern "C" void kernel_launch(void* const* d_in, const int* in_sizes, int n_in,
                              void* d_out, int out_size, void* d_ws, size_t ws_size,
                              hipStream_t stream) {
  const float* in_pc   = (const float*)d_in[0];
  const float* weights = (const float*)d_in[1];
  const float* bias    = (const float*)d_in[2];
  const float* w_w     = (const float*)d_in[3];
  const float* praw    = (const float*)d_in[4];
  const float* wres    = (const float*)d_in[5];
  const int*   nid     = (const int*)d_in[6];
  float* outp = (float*)d_out;

  const size_t NEED = 38010880;
  if (ws_size >= NEED) {
    __hip_bfloat16* ktb = (__hip_bfloat16*)d_ws;
    float* wrt  = (float*)((char*)d_ws + 131072);
    char*  Ahb  = (char*)d_ws + 262144;
    float* resb = (float*)((char*)d_ws + 33816576);
    prep2_kernel<<<256, 256, 0, stream>>>(weights, wres, ktb, wrt);
    hq_kernel<<<OUT_PNN, 256, 0, stream>>>(in_pc, w_w, praw, nid, wrt, Ahb, resb);
    gemm_kernel<<<256, 256, 0, stream>>>(Ahb, (const char*)ktb, resb, bias, outp);
  } else {
    float* kt2 = (float*)d_ws;
    float* wrt = kt2 + 65536;
    prep_kernel<<<256, 256, 0, stream>>>(weights, wres, kt2, wrt);
    fused_kernel<<<OUT_PNN, 256, 0, stream>>>(in_pc, bias, w_w, praw, nid, kt2, wrt, outp);
  }
}

// Round 3
// 94.209 us; speedup vs baseline: 1.5520x; 1.1102x over previous
//
#include <hip/hip_runtime.h>
#include <hip/hip_bf16.h>

#define IN_PNN  4096
#define OUT_PNN 2048
#define MM      16
#define WWN     32
#define ICC     32
#define OCC     64
#define NP      4          // output points per block (32 GEMM rows)
#define NT      16         // k-chunks of 64 (K = 1024)

typedef __attribute__((ext_vector_type(8))) short short8;
typedef __attribute__((ext_vector_type(4))) float f32x4;

// ws layout: [0, 131072)        ktb bf16 [64 o][1024 k]  (k = w*32 + i)
//            [131072, 139264)   wrt f32  [32 i][64 o]

__global__ __launch_bounds__(256) void prep2_kernel(const float* __restrict__ weights,
                                                    const float* __restrict__ wres,
                                                    __hip_bfloat16* __restrict__ ktb,
                                                    float* __restrict__ wrt) {
  int t = blockIdx.x * 256 + threadIdx.x;
  if (t < WWN * OCC * ICC) {               // 65536
    int o = t >> 10, k = t & 1023;
    int w = k >> 5, i = k & 31;
    ktb[t] = __float2bfloat16(weights[w * (OCC * ICC) + o * ICC + i]);
  }
  if (t < ICC * OCC) {                     // wrt[i*64+o] = wres[o*32+i]
    int i = t >> 6, o = t & 63;
    wrt[t] = wres[o * ICC + i];
  }
}

__global__ __launch_bounds__(512, 4) void fused3_kernel(
    const float* __restrict__ in_pc,   // [B][IN_PN][IC]
    const float* __restrict__ bias,    // [64]
    const float* __restrict__ ww,      // [OUT_PN][16][32]
    const float* __restrict__ praw,    // [OUT_PN][16]
    const int*   __restrict__ nid,     // [OUT_PN][16]
    const char*  __restrict__ ktb,     // bf16 [64][1024]
    const float* __restrict__ wrt,     // [32][64]
    float*       __restrict__ out) {   // [8][2048][64]

  __shared__ float s_ww[NP][WWN][MM];                   // masked, transposed [p][w][m], 8 KB
  __shared__ float s_wrt[ICC * OCC];                    // 8 KB
  __shared__ float s_praw[NP][MM];
  __shared__ float s_pinv[NP];
  __shared__ float s_q[NP * 8][33];                     // [r][i], padded
  __shared__ __align__(16) unsigned char s_A[2][4096];  // dbuf A-tile [32 r][128 B], XOR-swizzled
  __shared__ float s_acc[NP * 8][68];                   // conv acc staging

  const int tid   = threadIdx.x;
  const int pbase = blockIdx.x * NP;
  const int ph = tid >> 7;          // 0..3  (p slot)
  const int bg = (tid >> 5) & 3;    // 0..3  (b group; handles b=bg and b=bg+4)
  const int i  = tid & 31;          // channel

  // ---- neighbor ids (uniform across i-lanes) ----
  int ids[MM];
#pragma unroll
  for (int m = 0; m < MM; ++m) ids[m] = nid[(pbase + ph) * MM + m];

  // ---- gather neighbors into registers (coalesced 128B rows), issue early ----
  float nbr[2][MM];
#pragma unroll
  for (int d = 0; d < 2; ++d) {
    const int b = bg + 4 * d;
    const float* base = in_pc + (size_t)b * IN_PNN * ICC + i;
#pragma unroll
    for (int m = 0; m < MM; ++m) {
      int idc = ids[m] < IN_PNN ? ids[m] : IN_PNN - 1;   // clamp; masked via s_ww/s_praw
      nbr[d][m] = base[(size_t)idc * ICC];
    }
  }

  // ---- stage s_ww (masked + transposed), s_wrt, s_praw ----
  for (int e = tid; e < NP * MM * WWN; e += 512) {
    int pp = e >> 9, rem = e & 511, m = rem >> 5, w = rem & 31;
    int id = nid[(pbase + pp) * MM + m];
    s_ww[pp][w][m] = (id != IN_PNN) ? ww[(size_t)(pbase + pp) * (MM * WWN) + rem] : 0.f;
  }
  for (int e = tid; e < ICC * OCC; e += 512) s_wrt[e] = wrt[e];
  if (tid < NP * MM) {
    int pp = tid >> 4, m = tid & 15;
    int id = nid[(pbase + pp) * MM + m];
    s_praw[pp][m] = (id != IN_PNN) ? fabsf(praw[(pbase + pp) * MM + m]) : 0.f;
  }
  __syncthreads();
  if (tid < NP) {
    float s = 1e-8f;
#pragma unroll
    for (int m = 0; m < MM; ++m) s += s_praw[tid][m];
    s_pinv[tid] = 1.f / s;
  }
  __syncthreads();

  // ---- residual q[r][i] = sum_m p_norm[m] * nbr ----
  {
    float pv = s_pinv[ph];
#pragma unroll
    for (int d = 0; d < 2; ++d) {
      float q = 0.f;
#pragma unroll
      for (int m = 0; m < MM; ++m) q = fmaf(s_praw[ph][m], nbr[d][m], q);
      s_q[ph * 8 + bg + 4 * d][i] = q * pv;   // consumed after later barriers
    }
  }

  // ---- GEMM setup: 8 waves as 2 (row) x 4 (col); B-frags straight from global ----
  const int l  = tid & 63;
  const int wv = tid >> 6;
  const int wr = wv >> 2;                 // 0..1 -> rows wr*16..+15
  const int wc = wv & 3;                  // 0..3 -> cols wc*16..+15
  const char* Bbase = ktb + ((size_t)(wc * 16 + (l & 15)) * 1024 + (l >> 4) * 8) * 2;
  const int rA   = ph * 8 + bg;           // A-write base row (d adds 4)
  const int arow = wr * 16 + (l & 15);    // A-frag row

  f32x4 acc = {0.f, 0.f, 0.f, 0.f};
  uint4 Bc0 = *(const uint4*)(Bbase);
  uint4 Bc1 = *(const uint4*)(Bbase + 64);

#pragma unroll
  for (int t = 0; t < NT; ++t) {
    // h for w-pair {2t, 2t+1}, both b's: 64 FMA, ww via uniform-broadcast b128
    float h00 = 0.f, h01 = 0.f, h10 = 0.f, h11 = 0.f;
    {
      const float4* w0p = (const float4*)&s_ww[ph][2 * t][0];
      const float4* w1p = (const float4*)&s_ww[ph][2 * t + 1][0];
#pragma unroll
      for (int c = 0; c < 4; ++c) {
        float4 a0 = w0p[c], a1 = w1p[c];
        float n0 = nbr[0][4 * c + 0], n1 = nbr[0][4 * c + 1],
              n2 = nbr[0][4 * c + 2], n3 = nbr[0][4 * c + 3];
        float u0 = nbr[1][4 * c + 0], u1 = nbr[1][4 * c + 1],
              u2 = nbr[1][4 * c + 2], u3 = nbr[1][4 * c + 3];
        h00 = fmaf(a0.x, n0, h00); h00 = fmaf(a0.y, n1, h00);
        h00 = fmaf(a0.z, n2, h00); h00 = fmaf(a0.w, n3, h00);
        h01 = fmaf(a1.x, n0, h01); h01 = fmaf(a1.y, n1, h01);
        h01 = fmaf(a1.z, n2, h01); h01 = fmaf(a1.w, n3, h01);
        h10 = fmaf(a0.x, u0, h10); h10 = fmaf(a0.y, u1, h10);
        h10 = fmaf(a0.z, u2, h10); h10 = fmaf(a0.w, u3, h10);
        h11 = fmaf(a1.x, u0, h11); h11 = fmaf(a1.y, u1, h11);
        h11 = fmaf(a1.z, u2, h11); h11 = fmaf(a1.w, u3, h11);
      }
    }
    // write bf16 A-tile (dbuf, swizzle: 16B-chunk ^= row&7)
    {
      unsigned char* Abuf = s_A[t & 1];
#pragma unroll
      for (int d = 0; d < 2; ++d) {
        int r = rA + 4 * d;
        float v0 = d ? h10 : h00;          // w = 2t   -> kl = i
        float v1 = d ? h11 : h01;          // w = 2t+1 -> kl = 32+i
        int by0 = r * 128 + ((((i) >> 3) ^ (r & 7)) << 4) + ((i & 7) << 1);
        int by1 = r * 128 + ((((32 + i) >> 3) ^ (r & 7)) << 4) + ((i & 7) << 1);
        __hip_bfloat16 c0 = __float2bfloat16(v0);
        __hip_bfloat16 c1 = __float2bfloat16(v1);
        *(unsigned short*)(Abuf + by0) = *(unsigned short*)&c0;
        *(unsigned short*)(Abuf + by1) = *(unsigned short*)&c1;
      }
    }
    // prefetch next B chunk into regs
    uint4 Bn0, Bn1;
    if (t < NT - 1) {
      Bn0 = *(const uint4*)(Bbase + (size_t)(t + 1) * 128);
      Bn1 = *(const uint4*)(Bbase + (size_t)(t + 1) * 128 + 64);
    }
    __syncthreads();   // A-tile(t) complete; dbuf makes one barrier/chunk safe
    {
      const unsigned char* Abuf = s_A[t & 1];
      int k0 = (l >> 4) * 8;
      int by0 = arow * 128 + (((k0 >> 3) ^ (arow & 7)) << 4);
      int by1 = arow * 128 + ((((32 + k0) >> 3) ^ (arow & 7)) << 4);
      short8 aF0 = *(const short8*)(Abuf + by0);
      short8 aF1 = *(const short8*)(Abuf + by1);
      acc = __builtin_amdgcn_mfma_f32_16x16x32_bf16(aF0, *(short8*)&Bc0, acc, 0, 0, 0);
      acc = __builtin_amdgcn_mfma_f32_16x16x32_bf16(aF1, *(short8*)&Bc1, acc, 0, 0, 0);
    }
    if (t < NT - 1) { Bc0 = Bn0; Bc1 = Bn1; }
  }

  // ---- epilogue: acc -> LDS, then (r, o-quad) threads do residual+bias+ELU+mix ----
  {
    int row0 = wr * 16 + (l >> 4) * 4;
    int o    = wc * 16 + (l & 15);
#pragma unroll
    for (int j = 0; j < 4; ++j) s_acc[row0 + j][o] = acc[j];   // C: col=l&15, row=(l>>4)*4+j
  }
  __syncthreads();
  {
    int r  = tid >> 4;            // 0..31
    int og = (tid & 15) * 4;      // o quad
    float4 a  = *(const float4*)&s_acc[r][og];
    float4 rs = {0.f, 0.f, 0.f, 0.f};
#pragma unroll
    for (int i2 = 0; i2 < ICC; ++i2) {
      float  qv = s_q[r][i2];
      float4 wv = *(const float4*)&s_wrt[i2 * 64 + og];
      rs.x = fmaf(wv.x, qv, rs.x);
      rs.y = fmaf(wv.y, qv, rs.y);
      rs.z = fmaf(wv.z, qv, rs.z);
      rs.w = fmaf(wv.w, qv, rs.w);
    }
    float4 bz = *(const float4*)&bias[og];
    float c0 = a.x + bz.x, c1 = a.y + bz.y, c2 = a.z + bz.z, c3 = a.w + bz.w;
    c0 = (c0 > 0.f) ? c0 : (__expf(c0) - 1.f);
    c1 = (c1 > 0.f) ? c1 : (__expf(c1) - 1.f);
    c2 = (c2 > 0.f) ? c2 : (__expf(c2) - 1.f);
    c3 = (c3 > 0.f) ? c3 : (__expf(c3) - 1.f);
    const float rmix = 0.70710678118654752f;
    float4 o4;
    o4.x = rmix * (c0 + rs.x);
    o4.y = rmix * (c1 + rs.y);
    o4.z = rmix * (c2 + rs.z);
    o4.w = rmix * (c3 + rs.w);
    int b = r & 7, p = pbase + (r >> 3);
    *(float4*)&out[((size_t)b * OUT_PNN + p) * OCC + og] = o4;
  }
}

extern "C" void kernel_launch(void* const* d_in, const int* in_sizes, int n_in,
                              void* d_out, int out_size, void* d_ws, size_t ws_size,
                              hipStream_t stream) {
  const float* in_pc   = (const float*)d_in[0];
  const float* weights = (const float*)d_in[1];
  const float* bias    = (const float*)d_in[2];
  const float* w_w     = (const float*)d_in[3];
  const float* praw    = (const float*)d_in[4];
  const float* wres    = (const float*)d_in[5];
  const int*   nid     = (const int*)d_in[6];
  float* outp = (float*)d_out;

  __hip_bfloat16* ktb = (__hip_bfloat16*)d_ws;
  float* wrt = (float*)((char*)d_ws + 131072);

  prep2_kernel<<<256, 256, 0, stream>>>(weights, wres, ktb, wrt);
  fused3_kernel<<<OUT_PNN / NP, 512, 0, stream>>>(in_pc, bias, w_w, praw, nid,
                                                  (const char*)ktb, wrt, outp);
}